// Round 3
// baseline (733.244 us; speedup 1.0000x reference)
//
#include <hip/hip_runtime.h>

#define DM 128
#define DE 64

static constexpr int kB = 4;
static constexpr int kN = 50000;
static constexpr int kE = 600000;
static constexpr int kNodes = kB * kN;  // 200000

// workspace layout (float units; 4B-aligned ints share the arena)
// ASUM and CNT adjacent -> one memset clears both.
static constexpr size_t OFF_V    = 0;                               // nodes x 128
static constexpr size_t OFF_T    = OFF_V + (size_t)kNodes * DM;     // nodes x 64 (RESERVED, unused)
static constexpr size_t OFF_QA   = OFF_T + (size_t)kNodes * DE;     // nodes
static constexpr size_t OFF_KA   = OFF_QA + kNodes;                 // nodes
static constexpr size_t OFF_ASUM = OFF_KA + kNodes;                 // nodes   (zeroed)
static constexpr size_t OFF_CNT  = OFF_ASUM + kNodes;               // nodes   (int, zeroed)
static constexpr size_t OFF_AEXP = OFF_CNT + kNodes;                // edges
static constexpr size_t OFF_OFFS = OFF_AEXP + kE;                   // nodes (int)
static constexpr size_t OFF_POS  = OFF_OFFS + kNodes;               // edges (int)
static constexpr size_t OFF_BSUM = OFF_POS + kE;                    // 1024 (int)
static constexpr size_t OFF_BPRE = OFF_BSUM + 1024;                 // 1024 (int)
static constexpr size_t OFF_REC  = OFF_BPRE + 1024;                 // edges x float4 (16B aligned)
static constexpr size_t OFF_WQA  = OFF_REC + (size_t)kE * 4;        // 128
static constexpr size_t OFF_WKA  = OFF_WQA + DM;                    // 128
static constexpr size_t OFF_WEWA = OFF_WKA + DM;                    // 64
static constexpr size_t OFF_CB   = OFF_WEWA + DE;                   // 1
// bf16 split of Wv, transposed (j-major) and k-permuted for MFMA frag reads.
static constexpr size_t OFF_WTH  = OFF_CB + 4;
static constexpr size_t OFF_WTL  = OFF_WTH + 8192;
// packed bf16 Wev: wevp[k*64+l] = bf16(Wev[k][l]) | bf16(Wev[k][l+64])<<16
static constexpr size_t OFF_WEVP = OFF_WTL + 8192;                  // 4096 uints

static constexpr int kScanBlocks = (kNodes + 255) / 256;  // 782

typedef __attribute__((ext_vector_type(8))) short s8;     // 8 bf16 (4 VGPR)
typedef __attribute__((ext_vector_type(4))) float f4;     // MFMA acc

// RNE bf16 of f
__device__ inline unsigned short bf16rne(float f) {
  unsigned u = __float_as_uint(f);
  unsigned r = u + 0x7FFFu + ((u >> 16) & 1u);
  return (unsigned short)(r >> 16);
}

// RNE split: f = bf16(hi) + bf16(lo) + O(2^-17 rel)
__device__ inline void split2(float f, unsigned short& h, unsigned short& lo) {
  h = bf16rne(f);
  float fh = __uint_as_float((unsigned)h << 16);
  lo = bf16rne(f - fh);
}

// K0: fold Wa through the Q/K/Ew projections. wqa = Wq@Wa etc., cb = (bq+bk+bew)·Wa
__global__ void k0_combine(const float* __restrict__ Wq, const float* __restrict__ Wk,
                           const float* __restrict__ Wew, const float* __restrict__ Wa,
                           const float* __restrict__ bq, const float* __restrict__ bk,
                           const float* __restrict__ bew, float* __restrict__ ws) {
  int t = threadIdx.x;
  if (t < DM) {
    float a = 0.f;
    for (int j = 0; j < DM; ++j) a += Wq[t * DM + j] * Wa[j];
    ws[OFF_WQA + t] = a;
  } else if (t < 2 * DM) {
    int i = t - DM;
    float a = 0.f;
    for (int j = 0; j < DM; ++j) a += Wk[i * DM + j] * Wa[j];
    ws[OFF_WKA + i] = a;
  } else if (t < 2 * DM + DE) {
    int i = t - 2 * DM;
    float a = 0.f;
    for (int j = 0; j < DM; ++j) a += Wew[i * DM + j] * Wa[j];
    ws[OFF_WEWA + i] = a;
  }
  if (t == 0) {
    float a = 0.f;
    for (int j = 0; j < DM; ++j) a += (bq[j] + bk[j] + bew[j]) * Wa[j];
    ws[OFF_CB] = a;
  }
}

// K0b: split Wv into bf16 hi/lo (transposed + k-permuted for MFMA frags),
// and pack Wev columns (l, l+64) into the wevp table for k3's register epilogue.
__global__ __launch_bounds__(256) void k0b_wsplit(const float* __restrict__ Wv,
                                                  const float* __restrict__ Wev,
                                                  float* __restrict__ ws) {
  int idx = blockIdx.x * 256 + threadIdx.x;  // 0..16383
  int j = idx & 127, k = idx >> 7;
  float w = Wv[k * DM + j];
  unsigned short hi, lo;
  split2(w, hi, lo);
  int kc = k & 31;
  int kp = (k & ~31) | (((kc >> 2) & 3) << 3) | ((kc >> 4) << 2) | (kc & 3);
  ((short*)(ws + OFF_WTH))[j * 128 + kp] = (short)hi;
  ((short*)(ws + OFF_WTL))[j * 128 + kp] = (short)lo;
  if (idx < 4096) {
    int ke = idx >> 6, l = idx & 63;
    unsigned a = bf16rne(Wev[ke * DM + l]);
    unsigned b = bf16rne(Wev[ke * DM + 64 + l]);
    ((unsigned*)(ws + OFF_WEVP))[idx] = a | (b << 16);
  }
}

// K1: V = x@Wv + bv via split-bf16 MFMA (3 terms: hh + hl + lh, fp32 acc).
__global__ __launch_bounds__(512) void k1_node(const float* __restrict__ x,
                                               const float* __restrict__ bv,
                                               float* __restrict__ ws) {
  __shared__ short xh[128][128];
  __shared__ short xl[128][128];
  __shared__ short wh[128][128];
  __shared__ short wl[128][128];
  const int t = threadIdx.x;
  const int row0 = blockIdx.x * 128;

  // ---- stage W (pre-split, pre-permuted) ----
  const short* wtgh = (const short*)(ws + OFF_WTH);
  const short* wtgl = (const short*)(ws + OFF_WTL);
  #pragma unroll
  for (int i = 0; i < 4; ++i) {
    int idx = t + i * 512;  // 0..2047
    int j = idx >> 4;
    int c8 = (idx & 15) * 8;
    int col = (((c8 >> 3) ^ (j & 7)) << 3);
    *(int4*)&wh[j][col] = *(const int4*)(wtgh + j * 128 + c8);
    *(int4*)&wl[j][col] = *(const int4*)(wtgl + j * 128 + c8);
  }

  // ---- stage x: fp32 -> bf16 hi/lo, k-permuted + swizzled ----
  #pragma unroll
  for (int i = 0; i < 8; ++i) {
    int idx = t + i * 512;  // 0..4095
    int r = idx >> 5;
    int c4 = (idx & 31) * 4;
    int rg = row0 + r; if (rg > kNodes - 1) rg = kNodes - 1;
    float4 v = *(const float4*)(x + (size_t)rg * DM + c4);
    unsigned short h0, h1, h2, h3, l0, l1, l2, l3;
    split2(v.x, h0, l0); split2(v.y, h1, l1);
    split2(v.z, h2, l2); split2(v.w, h3, l3);
    int kc = c4 & 31;
    int cp = (c4 & ~31) | (((kc >> 2) & 3) << 3) | ((kc >> 4) << 2);
    int col = ((((cp >> 3) ^ (r & 7)) << 3)) | (cp & 7);
    *(short4*)&xh[r][col] = make_short4((short)h0, (short)h1, (short)h2, (short)h3);
    *(short4*)&xl[r][col] = make_short4((short)l0, (short)l1, (short)l2, (short)l3);
  }

  // ---- fused qa/ka (exact fp32) ----
  if (t < 256) {
    int r = t & 127;
    int rg = row0 + r;
    if (rg < kNodes) {
      const float* wvec = (t < 128) ? (ws + OFF_WQA) : (ws + OFF_WKA);
      const float* xr = x + (size_t)rg * DM;
      float a = 0.f;
      #pragma unroll
      for (int k = 0; k < DM; k += 4) {
        float4 xv = *(const float4*)(xr + k);
        float4 wv = *(const float4*)(wvec + k);
        a += xv.x * wv.x + xv.y * wv.y + xv.z * wv.z + xv.w * wv.w;
      }
      ((t < 128) ? (ws + OFF_QA) : (ws + OFF_KA))[rg] = a;
    }
  }

  __syncthreads();

  const int l = t & 63;
  const int wid = t >> 6;   // 0..7
  const int wr = wid >> 1;  // 0..3 -> rows wr*32
  const int wc = wid & 1;   // 0..1 -> cols wc*64
  const int lrow = l & 15;
  const int lg = l >> 4;

  f4 acc[2][4];
  #pragma unroll
  for (int i = 0; i < 2; ++i)
    #pragma unroll
    for (int j = 0; j < 4; ++j) acc[i][j] = (f4){0.f, 0.f, 0.f, 0.f};

  #pragma unroll
  for (int ks = 0; ks < 4; ++ks) {
    s8 ah[2], al[2], bh[4], bl[4];
    #pragma unroll
    for (int i = 0; i < 2; ++i) {
      int r = wr * 32 + i * 16 + lrow;
      int col = (((ks * 4 + lg) ^ (r & 7)) << 3);
      ah[i] = *(const s8*)&xh[r][col];
      al[i] = *(const s8*)&xl[r][col];
    }
    #pragma unroll
    for (int j = 0; j < 4; ++j) {
      int r = wc * 64 + j * 16 + lrow;
      int col = (((ks * 4 + lg) ^ (r & 7)) << 3);
      bh[j] = *(const s8*)&wh[r][col];
      bl[j] = *(const s8*)&wl[r][col];
    }
    #pragma unroll
    for (int i = 0; i < 2; ++i)
      #pragma unroll
      for (int j = 0; j < 4; ++j) {
        acc[i][j] = __builtin_amdgcn_mfma_f32_16x16x32_bf16(ah[i], bh[j], acc[i][j], 0, 0, 0);
        acc[i][j] = __builtin_amdgcn_mfma_f32_16x16x32_bf16(ah[i], bl[j], acc[i][j], 0, 0, 0);
        acc[i][j] = __builtin_amdgcn_mfma_f32_16x16x32_bf16(al[i], bh[j], acc[i][j], 0, 0, 0);
      }
  }

  // epilogue: D row = (l>>4)*4 + reg, col = l&15 (m89-verified layout)
  float* V = ws + OFF_V;
  #pragma unroll
  for (int i = 0; i < 2; ++i) {
    int rb = row0 + wr * 32 + i * 16 + lg * 4;
    #pragma unroll
    for (int j = 0; j < 4; ++j) {
      int colj = wc * 64 + j * 16 + lrow;
      float bvv = bv[colj];
      #pragma unroll
      for (int q = 0; q < 4; ++q) {
        int rr = rb + q;
        if (rr < kNodes) V[(size_t)rr * DM + colj] = acc[i][j][q] + bvv;
      }
    }
  }
}

// K2: per-edge logit -> exp -> atomic segment-sum over (b,dst); fused src-degree count
__global__ __launch_bounds__(256) void k2_edge1(const int* __restrict__ ei,
                                                const int* __restrict__ bidx,
                                                const float* __restrict__ eemb,
                                                float* __restrict__ ws) {
  __shared__ float wewa_s[DE];
  __shared__ float cb_s;
  int t = threadIdx.x;
  if (t < DE) wewa_s[t] = ws[OFF_WEWA + t];
  if (t == DE) cb_s = ws[OFF_CB];
  __syncthreads();
  int e = blockIdx.x * 256 + t;
  if (e >= kE) return;
  int s = ei[e];
  int d = ei[kE + e];
  int b = bidx[e];
  const float4* emb = (const float4*)(eemb + (size_t)e * DE);
  float a = 0.f;
  #pragma unroll
  for (int i = 0; i < 16; ++i) {
    float4 v = emb[i];
    a += v.x * wewa_s[i * 4] + v.y * wewa_s[i * 4 + 1] +
         v.z * wewa_s[i * 4 + 2] + v.w * wewa_s[i * 4 + 3];
  }
  float logit = (ws[OFF_QA + b * kN + s] + ws[OFF_KA + b * kN + d] + a + cb_s) * 0.25f;
  float ex = __expf(logit);
  ws[OFF_AEXP + e] = ex;
  unsafeAtomicAdd(&ws[OFF_ASUM + b * kN + d], ex);
  int* wsi = (int*)ws;
  int gs = b * kN + s;
  wsi[OFF_POS + e] = atomicAdd(&wsi[OFF_CNT + gs], 1);
}

// scan step 1: block-local exclusive scan of cnt, block totals to bsum
__global__ __launch_bounds__(256) void k_scan1(float* __restrict__ ws) {
  __shared__ int sh[256];
  int* wsi = (int*)ws;
  const int tid = threadIdx.x;
  const int i = blockIdx.x * 256 + tid;
  int v = (i < kNodes) ? wsi[OFF_CNT + i] : 0;
  int acc = v;
  sh[tid] = acc;
  __syncthreads();
  #pragma unroll
  for (int ofs = 1; ofs < 256; ofs <<= 1) {
    int add = (tid >= ofs) ? sh[tid - ofs] : 0;
    __syncthreads();
    acc += add;
    sh[tid] = acc;
    __syncthreads();
  }
  if (i < kNodes) wsi[OFF_OFFS + i] = acc - v;
  if (tid == 255) wsi[OFF_BSUM + blockIdx.x] = acc;
}

// scan step 2: exclusive scan of block sums (782 <= 1024, single block).
__global__ __launch_bounds__(1024) void k_scan2(float* __restrict__ ws) {
  __shared__ int sh[1024];
  int* wsi = (int*)ws;
  const int tid = threadIdx.x;
  int v = (tid < kScanBlocks) ? wsi[OFF_BSUM + tid] : 0;
  int acc = v;
  sh[tid] = acc;
  __syncthreads();
  for (int ofs = 1; ofs < 1024; ofs <<= 1) {
    int add = (tid >= ofs) ? sh[tid - ofs] : 0;
    __syncthreads();
    acc += add;
    sh[tid] = acc;
    __syncthreads();
  }
  wsi[OFF_BPRE + tid] = acc - v;
}

// fill: resolve each edge into its CSR slot as a 16B record {alpha, gd, e, pad}
__global__ __launch_bounds__(256) void k_fill(const int* __restrict__ ei,
                                              const int* __restrict__ bidx,
                                              float* __restrict__ ws) {
  int e = blockIdx.x * 256 + threadIdx.x;
  if (e >= kE) return;
  int s = ei[e];
  int d = ei[kE + e];
  int b = bidx[e];
  int gs = b * kN + s;
  int gd = b * kN + d;
  const int* wsi = (const int*)ws;
  float alpha = ws[OFF_AEXP + e] / (ws[OFF_ASUM + gd] + 1e-9f);
  int p = wsi[OFF_OFFS + gs] + wsi[OFF_BPRE + (gs >> 8)] + wsi[OFF_POS + e];
  float4 r;
  r.x = alpha;
  r.y = __int_as_float(gd);
  r.z = __int_as_float(e);
  r.w = 0.f;
  ((float4*)(ws + OFF_REC))[p] = r;
}

// gather + FUSED Wev epilogue: grid-stride waves (amortizes the 64-reg packed
// Wev load over ~12 nodes). Per node: 4 edges/round with 12 gathers in flight;
// then out = o + ss*bev + sum_k tac_k * Wev[k][:] entirely in registers via
// readlane broadcast (VALU pipe, no LDS port). T never touches memory; k4 gone.
__global__ __launch_bounds__(256) void k3_gather(const float* __restrict__ eemb,
                                                 const float* __restrict__ bev,
                                                 float* __restrict__ ws,
                                                 float* __restrict__ out) {
  const int lane = threadIdx.x & 63;
  const int gw = (blockIdx.x * 256 + threadIdx.x) >> 6;
  const int nw = (gridDim.x * 256) >> 6;
  const int* wsi = (const int*)ws;
  const float* V = ws + OFF_V;
  const float4* rec = (const float4*)(ws + OFF_REC);
  const float bev0 = bev[lane];
  const float bev1 = bev[64 + lane];

  // packed Wev column pair (lane, lane+64) for all 64 k — held in registers
  const unsigned* wevpg = (const unsigned*)(ws + OFF_WEVP);
  unsigned wevp[64];
  #pragma unroll
  for (int k = 0; k < 64; ++k) wevp[k] = wevpg[k * 64 + lane];

  for (int g = gw; g < kNodes; g += nw) {
    const int start = wsi[OFF_OFFS + g] + wsi[OFF_BPRE + (g >> 8)];
    const int deg = wsi[OFF_CNT + g];
    float o0 = 0.f, o1 = 0.f, tac = 0.f, ss = 0.f;
    for (int base = 0; base < deg; base += 4) {
      const int rem = deg - base;  // >= 1, wave-uniform
      const int c1 = (rem > 1) ? 1 : 0;
      const int c2 = (rem > 2) ? 2 : c1;
      const int c3 = (rem > 3) ? 3 : c2;
      float4 r0 = rec[start + base];
      float4 r1 = rec[start + base + c1];
      float4 r2 = rec[start + base + c2];
      float4 r3 = rec[start + base + c3];
      float a0 = r0.x;
      float a1 = (rem > 1) ? r1.x : 0.f;
      float a2 = (rem > 2) ? r2.x : 0.f;
      float a3 = (rem > 3) ? r3.x : 0.f;
      const size_t gd0 = (size_t)__float_as_int(r0.y) * DM;
      const size_t gd1 = (size_t)__float_as_int(r1.y) * DM;
      const size_t gd2 = (size_t)__float_as_int(r2.y) * DM;
      const size_t gd3 = (size_t)__float_as_int(r3.y) * DM;
      const size_t e0 = (size_t)__float_as_int(r0.z) * DE;
      const size_t e1 = (size_t)__float_as_int(r1.z) * DE;
      const size_t e2 = (size_t)__float_as_int(r2.z) * DE;
      const size_t e3 = (size_t)__float_as_int(r3.z) * DE;
      float v00 = V[gd0 + lane],      v01 = V[gd1 + lane];
      float v02 = V[gd2 + lane],      v03 = V[gd3 + lane];
      float v10 = V[gd0 + 64 + lane], v11 = V[gd1 + 64 + lane];
      float v12 = V[gd2 + 64 + lane], v13 = V[gd3 + 64 + lane];
      float m0 = eemb[e0 + lane],     m1 = eemb[e1 + lane];
      float m2 = eemb[e2 + lane],     m3 = eemb[e3 + lane];
      o0 += a0 * v00 + a1 * v01 + a2 * v02 + a3 * v03;
      o1 += a0 * v10 + a1 * v11 + a2 * v12 + a3 * v13;
      tac += a0 * m0 + a1 * m1 + a2 * m2 + a3 * m3;
      ss += a0 + a1 + a2 + a3;
    }
    float res0 = o0 + ss * bev0;
    float res1 = o1 + ss * bev1;
    // T-row (tac, one dim per lane) x Wev, via readlane broadcast
    #pragma unroll
    for (int k = 0; k < 64; ++k) {
      float tk = __int_as_float(__builtin_amdgcn_readlane(__float_as_int(tac), k));
      unsigned p = wevp[k];
      res0 = fmaf(tk, __uint_as_float(p << 16), res0);
      res1 = fmaf(tk, __uint_as_float(p & 0xFFFF0000u), res1);
    }
    out[(size_t)g * DM + lane] = res0;
    out[(size_t)g * DM + 64 + lane] = res1;
  }
}

extern "C" void kernel_launch(void* const* d_in, const int* in_sizes, int n_in,
                              void* d_out, int out_size, void* d_ws, size_t ws_size,
                              hipStream_t stream) {
  const float* x    = (const float*)d_in[0];
  const int*   ei   = (const int*)d_in[1];
  const float* eemb = (const float*)d_in[2];
  const int*   bidx = (const int*)d_in[3];
  // d_in[4] = n_heads (d_h = 16 -> scale 0.25 hard-coded)
  const float* Wq  = (const float*)d_in[5];
  const float* bq  = (const float*)d_in[6];
  const float* Wk  = (const float*)d_in[7];
  const float* bk  = (const float*)d_in[8];
  const float* Wv  = (const float*)d_in[9];
  const float* bv  = (const float*)d_in[10];
  const float* Wew = (const float*)d_in[11];
  const float* bew = (const float*)d_in[12];
  const float* Wev = (const float*)d_in[13];
  const float* bev = (const float*)d_in[14];
  const float* Wa  = (const float*)d_in[15];
  float* ws  = (float*)d_ws;
  float* out = (float*)d_out;

  // ASUM (float) and CNT (int) are adjacent: one clear for both
  hipMemsetAsync(ws + OFF_ASUM, 0, (size_t)2 * kNodes * sizeof(float), stream);

  k0_combine<<<1, 320, 0, stream>>>(Wq, Wk, Wew, Wa, bq, bk, bew, ws);
  k0b_wsplit<<<64, 256, 0, stream>>>(Wv, Wev, ws);
  k1_node<<<(kNodes + 127) / 128, 512, 0, stream>>>(x, bv, ws);
  k2_edge1<<<(kE + 255) / 256, 256, 0, stream>>>(ei, bidx, eemb, ws);
  k_scan1<<<kScanBlocks, 256, 0, stream>>>(ws);
  k_scan2<<<1, 1024, 0, stream>>>(ws);
  k_fill<<<(kE + 255) / 256, 256, 0, stream>>>(ei, bidx, ws);
  k3_gather<<<4096, 256, 0, stream>>>(eemb, bev, ws, out);
}

// Round 4
// 713.476 us; speedup vs baseline: 1.0277x; 1.0277x over previous
//
#include <hip/hip_runtime.h>

#define DM 128
#define DE 64

static constexpr int kB = 4;
static constexpr int kN = 50000;
static constexpr int kE = 600000;
static constexpr int kNodes = kB * kN;  // 200000

// workspace layout (float units; 4B-aligned ints share the arena)
// ASUM and CNT adjacent -> one memset clears both.
static constexpr size_t OFF_V    = 0;                               // nodes x 128
static constexpr size_t OFF_T    = OFF_V + (size_t)kNodes * DM;     // nodes x 64 (RESERVED, unused)
static constexpr size_t OFF_QA   = OFF_T + (size_t)kNodes * DE;     // nodes
static constexpr size_t OFF_KA   = OFF_QA + kNodes;                 // nodes
static constexpr size_t OFF_ASUM = OFF_KA + kNodes;                 // nodes   (zeroed)
static constexpr size_t OFF_CNT  = OFF_ASUM + kNodes;               // nodes   (int, zeroed)
static constexpr size_t OFF_AEXP = OFF_CNT + kNodes;                // edges
static constexpr size_t OFF_OFFS = OFF_AEXP + kE;                   // nodes (int)
static constexpr size_t OFF_POS  = OFF_OFFS + kNodes;               // edges (int)
static constexpr size_t OFF_BSUM = OFF_POS + kE;                    // 1024 (int)
static constexpr size_t OFF_BPRE = OFF_BSUM + 1024;                 // 1024 (int)
static constexpr size_t OFF_REC  = OFF_BPRE + 1024;                 // edges x float4 (16B aligned)
static constexpr size_t OFF_WQA  = OFF_REC + (size_t)kE * 4;        // 128
static constexpr size_t OFF_WKA  = OFF_WQA + DM;                    // 128
static constexpr size_t OFF_WEWA = OFF_WKA + DM;                    // 64
static constexpr size_t OFF_CB   = OFF_WEWA + DE;                   // 1
// bf16 split of Wv, transposed (j-major) and k-permuted for MFMA frag reads.
static constexpr size_t OFF_WTH  = OFF_CB + 4;
static constexpr size_t OFF_WTL  = OFF_WTH + 8192;
// packed bf16 Wev, pair-interleaved: wevp[(k>>1)*128 + l*2 + (k&1)] =
//   bf16(Wev[k][l]) | bf16(Wev[k][l+64])<<16   (4096 uints)
static constexpr size_t OFF_WEVP = OFF_WTL + 8192;

static constexpr int kScanBlocks = (kNodes + 255) / 256;  // 782

typedef __attribute__((ext_vector_type(8))) short s8;     // 8 bf16 (4 VGPR)
typedef __attribute__((ext_vector_type(4))) float f4;     // MFMA acc

// RNE bf16 of f
__device__ inline unsigned short bf16rne(float f) {
  unsigned u = __float_as_uint(f);
  unsigned r = u + 0x7FFFu + ((u >> 16) & 1u);
  return (unsigned short)(r >> 16);
}

// RNE split: f = bf16(hi) + bf16(lo) + O(2^-17 rel)
__device__ inline void split2(float f, unsigned short& h, unsigned short& lo) {
  h = bf16rne(f);
  float fh = __uint_as_float((unsigned)h << 16);
  lo = bf16rne(f - fh);
}

// K0: fold Wa through the Q/K/Ew projections. wqa = Wq@Wa etc., cb = (bq+bk+bew)·Wa
__global__ void k0_combine(const float* __restrict__ Wq, const float* __restrict__ Wk,
                           const float* __restrict__ Wew, const float* __restrict__ Wa,
                           const float* __restrict__ bq, const float* __restrict__ bk,
                           const float* __restrict__ bew, float* __restrict__ ws) {
  int t = threadIdx.x;
  if (t < DM) {
    float a = 0.f;
    for (int j = 0; j < DM; ++j) a += Wq[t * DM + j] * Wa[j];
    ws[OFF_WQA + t] = a;
  } else if (t < 2 * DM) {
    int i = t - DM;
    float a = 0.f;
    for (int j = 0; j < DM; ++j) a += Wk[i * DM + j] * Wa[j];
    ws[OFF_WKA + i] = a;
  } else if (t < 2 * DM + DE) {
    int i = t - 2 * DM;
    float a = 0.f;
    for (int j = 0; j < DM; ++j) a += Wew[i * DM + j] * Wa[j];
    ws[OFF_WEWA + i] = a;
  }
  if (t == 0) {
    float a = 0.f;
    for (int j = 0; j < DM; ++j) a += (bq[j] + bk[j] + bew[j]) * Wa[j];
    ws[OFF_CB] = a;
  }
}

// K0b: split Wv into bf16 hi/lo (transposed + k-permuted for MFMA frags),
// and pack Wev pair-interleaved for k3's LDS epilogue.
__global__ __launch_bounds__(256) void k0b_wsplit(const float* __restrict__ Wv,
                                                  const float* __restrict__ Wev,
                                                  float* __restrict__ ws) {
  int idx = blockIdx.x * 256 + threadIdx.x;  // 0..16383
  int j = idx & 127, k = idx >> 7;
  float w = Wv[k * DM + j];
  unsigned short hi, lo;
  split2(w, hi, lo);
  int kc = k & 31;
  int kp = (k & ~31) | (((kc >> 2) & 3) << 3) | ((kc >> 4) << 2) | (kc & 3);
  ((short*)(ws + OFF_WTH))[j * 128 + kp] = (short)hi;
  ((short*)(ws + OFF_WTL))[j * 128 + kp] = (short)lo;
  if (idx < 4096) {
    int ke = idx >> 6, l = idx & 63;
    unsigned a = bf16rne(Wev[ke * DM + l]);
    unsigned b = bf16rne(Wev[ke * DM + 64 + l]);
    ((unsigned*)(ws + OFF_WEVP))[(ke >> 1) * 128 + l * 2 + (ke & 1)] = a | (b << 16);
  }
}

// K1: V = x@Wv + bv via split-bf16 MFMA (3 terms: hh + hl + lh, fp32 acc).
__global__ __launch_bounds__(512) void k1_node(const float* __restrict__ x,
                                               const float* __restrict__ bv,
                                               float* __restrict__ ws) {
  __shared__ short xh[128][128];
  __shared__ short xl[128][128];
  __shared__ short wh[128][128];
  __shared__ short wl[128][128];
  const int t = threadIdx.x;
  const int row0 = blockIdx.x * 128;

  // ---- stage W (pre-split, pre-permuted) ----
  const short* wtgh = (const short*)(ws + OFF_WTH);
  const short* wtgl = (const short*)(ws + OFF_WTL);
  #pragma unroll
  for (int i = 0; i < 4; ++i) {
    int idx = t + i * 512;  // 0..2047
    int j = idx >> 4;
    int c8 = (idx & 15) * 8;
    int col = (((c8 >> 3) ^ (j & 7)) << 3);
    *(int4*)&wh[j][col] = *(const int4*)(wtgh + j * 128 + c8);
    *(int4*)&wl[j][col] = *(const int4*)(wtgl + j * 128 + c8);
  }

  // ---- stage x: fp32 -> bf16 hi/lo, k-permuted + swizzled ----
  #pragma unroll
  for (int i = 0; i < 8; ++i) {
    int idx = t + i * 512;  // 0..4095
    int r = idx >> 5;
    int c4 = (idx & 31) * 4;
    int rg = row0 + r; if (rg > kNodes - 1) rg = kNodes - 1;
    float4 v = *(const float4*)(x + (size_t)rg * DM + c4);
    unsigned short h0, h1, h2, h3, l0, l1, l2, l3;
    split2(v.x, h0, l0); split2(v.y, h1, l1);
    split2(v.z, h2, l2); split2(v.w, h3, l3);
    int kc = c4 & 31;
    int cp = (c4 & ~31) | (((kc >> 2) & 3) << 3) | ((kc >> 4) << 2);
    int col = ((((cp >> 3) ^ (r & 7)) << 3)) | (cp & 7);
    *(short4*)&xh[r][col] = make_short4((short)h0, (short)h1, (short)h2, (short)h3);
    *(short4*)&xl[r][col] = make_short4((short)l0, (short)l1, (short)l2, (short)l3);
  }

  // ---- fused qa/ka (exact fp32) ----
  if (t < 256) {
    int r = t & 127;
    int rg = row0 + r;
    if (rg < kNodes) {
      const float* wvec = (t < 128) ? (ws + OFF_WQA) : (ws + OFF_WKA);
      const float* xr = x + (size_t)rg * DM;
      float a = 0.f;
      #pragma unroll
      for (int k = 0; k < DM; k += 4) {
        float4 xv = *(const float4*)(xr + k);
        float4 wv = *(const float4*)(wvec + k);
        a += xv.x * wv.x + xv.y * wv.y + xv.z * wv.z + xv.w * wv.w;
      }
      ((t < 128) ? (ws + OFF_QA) : (ws + OFF_KA))[rg] = a;
    }
  }

  __syncthreads();

  const int l = t & 63;
  const int wid = t >> 6;   // 0..7
  const int wr = wid >> 1;  // 0..3 -> rows wr*32
  const int wc = wid & 1;   // 0..1 -> cols wc*64
  const int lrow = l & 15;
  const int lg = l >> 4;

  f4 acc[2][4];
  #pragma unroll
  for (int i = 0; i < 2; ++i)
    #pragma unroll
    for (int j = 0; j < 4; ++j) acc[i][j] = (f4){0.f, 0.f, 0.f, 0.f};

  #pragma unroll
  for (int ks = 0; ks < 4; ++ks) {
    s8 ah[2], al[2], bh[4], bl[4];
    #pragma unroll
    for (int i = 0; i < 2; ++i) {
      int r = wr * 32 + i * 16 + lrow;
      int col = (((ks * 4 + lg) ^ (r & 7)) << 3);
      ah[i] = *(const s8*)&xh[r][col];
      al[i] = *(const s8*)&xl[r][col];
    }
    #pragma unroll
    for (int j = 0; j < 4; ++j) {
      int r = wc * 64 + j * 16 + lrow;
      int col = (((ks * 4 + lg) ^ (r & 7)) << 3);
      bh[j] = *(const s8*)&wh[r][col];
      bl[j] = *(const s8*)&wl[r][col];
    }
    #pragma unroll
    for (int i = 0; i < 2; ++i)
      #pragma unroll
      for (int j = 0; j < 4; ++j) {
        acc[i][j] = __builtin_amdgcn_mfma_f32_16x16x32_bf16(ah[i], bh[j], acc[i][j], 0, 0, 0);
        acc[i][j] = __builtin_amdgcn_mfma_f32_16x16x32_bf16(ah[i], bl[j], acc[i][j], 0, 0, 0);
        acc[i][j] = __builtin_amdgcn_mfma_f32_16x16x32_bf16(al[i], bh[j], acc[i][j], 0, 0, 0);
      }
  }

  // epilogue: D row = (l>>4)*4 + reg, col = l&15 (m89-verified layout)
  float* V = ws + OFF_V;
  #pragma unroll
  for (int i = 0; i < 2; ++i) {
    int rb = row0 + wr * 32 + i * 16 + lg * 4;
    #pragma unroll
    for (int j = 0; j < 4; ++j) {
      int colj = wc * 64 + j * 16 + lrow;
      float bvv = bv[colj];
      #pragma unroll
      for (int q = 0; q < 4; ++q) {
        int rr = rb + q;
        if (rr < kNodes) V[(size_t)rr * DM + colj] = acc[i][j][q] + bvv;
      }
    }
  }
}

// K2: per-edge logit -> exp -> atomic segment-sum over (b,dst); fused src-degree count
__global__ __launch_bounds__(256) void k2_edge1(const int* __restrict__ ei,
                                                const int* __restrict__ bidx,
                                                const float* __restrict__ eemb,
                                                float* __restrict__ ws) {
  __shared__ float wewa_s[DE];
  __shared__ float cb_s;
  int t = threadIdx.x;
  if (t < DE) wewa_s[t] = ws[OFF_WEWA + t];
  if (t == DE) cb_s = ws[OFF_CB];
  __syncthreads();
  int e = blockIdx.x * 256 + t;
  if (e >= kE) return;
  int s = ei[e];
  int d = ei[kE + e];
  int b = bidx[e];
  const float4* emb = (const float4*)(eemb + (size_t)e * DE);
  float a = 0.f;
  #pragma unroll
  for (int i = 0; i < 16; ++i) {
    float4 v = emb[i];
    a += v.x * wewa_s[i * 4] + v.y * wewa_s[i * 4 + 1] +
         v.z * wewa_s[i * 4 + 2] + v.w * wewa_s[i * 4 + 3];
  }
  float logit = (ws[OFF_QA + b * kN + s] + ws[OFF_KA + b * kN + d] + a + cb_s) * 0.25f;
  float ex = __expf(logit);
  ws[OFF_AEXP + e] = ex;
  unsafeAtomicAdd(&ws[OFF_ASUM + b * kN + d], ex);
  int* wsi = (int*)ws;
  int gs = b * kN + s;
  wsi[OFF_POS + e] = atomicAdd(&wsi[OFF_CNT + gs], 1);
}

// scan step 1: block-local exclusive scan of cnt, block totals to bsum
__global__ __launch_bounds__(256) void k_scan1(float* __restrict__ ws) {
  __shared__ int sh[256];
  int* wsi = (int*)ws;
  const int tid = threadIdx.x;
  const int i = blockIdx.x * 256 + tid;
  int v = (i < kNodes) ? wsi[OFF_CNT + i] : 0;
  int acc = v;
  sh[tid] = acc;
  __syncthreads();
  #pragma unroll
  for (int ofs = 1; ofs < 256; ofs <<= 1) {
    int add = (tid >= ofs) ? sh[tid - ofs] : 0;
    __syncthreads();
    acc += add;
    sh[tid] = acc;
    __syncthreads();
  }
  if (i < kNodes) wsi[OFF_OFFS + i] = acc - v;
  if (tid == 255) wsi[OFF_BSUM + blockIdx.x] = acc;
}

// scan step 2: exclusive scan of block sums (782 <= 1024, single block).
__global__ __launch_bounds__(1024) void k_scan2(float* __restrict__ ws) {
  __shared__ int sh[1024];
  int* wsi = (int*)ws;
  const int tid = threadIdx.x;
  int v = (tid < kScanBlocks) ? wsi[OFF_BSUM + tid] : 0;
  int acc = v;
  sh[tid] = acc;
  __syncthreads();
  for (int ofs = 1; ofs < 1024; ofs <<= 1) {
    int add = (tid >= ofs) ? sh[tid - ofs] : 0;
    __syncthreads();
    acc += add;
    sh[tid] = acc;
    __syncthreads();
  }
  wsi[OFF_BPRE + tid] = acc - v;
}

// fill: resolve each edge into its CSR slot as a 16B record {alpha, gd, e, pad}
__global__ __launch_bounds__(256) void k_fill(const int* __restrict__ ei,
                                              const int* __restrict__ bidx,
                                              float* __restrict__ ws) {
  int e = blockIdx.x * 256 + threadIdx.x;
  if (e >= kE) return;
  int s = ei[e];
  int d = ei[kE + e];
  int b = bidx[e];
  int gs = b * kN + s;
  int gd = b * kN + d;
  const int* wsi = (const int*)ws;
  float alpha = ws[OFF_AEXP + e] / (ws[OFF_ASUM + gd] + 1e-9f);
  int p = wsi[OFF_OFFS + gs] + wsi[OFF_BPRE + (gs >> 8)] + wsi[OFF_POS + e];
  float4 r;
  r.x = alpha;
  r.y = __int_as_float(gd);
  r.z = __int_as_float(e);
  r.w = 0.f;
  ((float4*)(ws + OFF_REC))[p] = r;
}

// gather + fused Wev epilogue, LDS edition (R3 post-mortem: the 64-VGPR wevp
// table cut occupancy 75->21% and tripled k3's time; all epilogue state now
// lives in LDS so VGPR stays ~48 and the latency-bound gather keeps its TLP).
// wevp staged once per block (16 KB); per node the wave writes its T-row to a
// per-wave LDS slot and re-reads it pairwise as a uniform broadcast.
__global__ __launch_bounds__(256) void k3_gather(const float* __restrict__ eemb,
                                                 const float* __restrict__ bev,
                                                 float* __restrict__ ws,
                                                 float* __restrict__ out) {
  __shared__ unsigned wevp_s[4096];  // [k>>1][lane][k&1] packed bf16 col-pairs
  __shared__ float tac_s[4][64];     // per-wave T row
  const int t = threadIdx.x;
  const int lane = t & 63;
  const int wid = t >> 6;

  const unsigned* wevpg = (const unsigned*)(ws + OFF_WEVP);
  #pragma unroll
  for (int i = 0; i < 16; ++i) wevp_s[t + i * 256] = wevpg[t + i * 256];
  __syncthreads();

  const int gw = (blockIdx.x * 256 + t) >> 6;
  const int nw = (gridDim.x * 256) >> 6;
  const int* wsi = (const int*)ws;
  const float* V = ws + OFF_V;
  const float4* rec = (const float4*)(ws + OFF_REC);
  const float bev0 = bev[lane];
  const float bev1 = bev[64 + lane];

  for (int g = gw; g < kNodes; g += nw) {
    const int start = wsi[OFF_OFFS + g] + wsi[OFF_BPRE + (g >> 8)];
    const int deg = wsi[OFF_CNT + g];
    float o0 = 0.f, o1 = 0.f, tac = 0.f, ss = 0.f;
    for (int base = 0; base < deg; base += 4) {
      const int rem = deg - base;  // >= 1, wave-uniform
      const int c1 = (rem > 1) ? 1 : 0;
      const int c2 = (rem > 2) ? 2 : c1;
      const int c3 = (rem > 3) ? 3 : c2;
      float4 r0 = rec[start + base];
      float4 r1 = rec[start + base + c1];
      float4 r2 = rec[start + base + c2];
      float4 r3 = rec[start + base + c3];
      float a0 = r0.x;
      float a1 = (rem > 1) ? r1.x : 0.f;
      float a2 = (rem > 2) ? r2.x : 0.f;
      float a3 = (rem > 3) ? r3.x : 0.f;
      const size_t gd0 = (size_t)__float_as_int(r0.y) * DM;
      const size_t gd1 = (size_t)__float_as_int(r1.y) * DM;
      const size_t gd2 = (size_t)__float_as_int(r2.y) * DM;
      const size_t gd3 = (size_t)__float_as_int(r3.y) * DM;
      const size_t e0 = (size_t)__float_as_int(r0.z) * DE;
      const size_t e1 = (size_t)__float_as_int(r1.z) * DE;
      const size_t e2 = (size_t)__float_as_int(r2.z) * DE;
      const size_t e3 = (size_t)__float_as_int(r3.z) * DE;
      float v00 = V[gd0 + lane],      v01 = V[gd1 + lane];
      float v02 = V[gd2 + lane],      v03 = V[gd3 + lane];
      float v10 = V[gd0 + 64 + lane], v11 = V[gd1 + 64 + lane];
      float v12 = V[gd2 + 64 + lane], v13 = V[gd3 + 64 + lane];
      float m0 = eemb[e0 + lane],     m1 = eemb[e1 + lane];
      float m2 = eemb[e2 + lane],     m3 = eemb[e3 + lane];
      o0 += a0 * v00 + a1 * v01 + a2 * v02 + a3 * v03;
      o1 += a0 * v10 + a1 * v11 + a2 * v12 + a3 * v13;
      tac += a0 * m0 + a1 * m1 + a2 * m2 + a3 * m3;
      ss += a0 + a1 + a2 + a3;
    }
    // T-row x Wev via LDS broadcast (no VGPR table, halved dep chains)
    tac_s[wid][lane] = tac;
    float res0 = o0 + ss * bev0;
    float res1 = o1 + ss * bev1;
    float r0b = 0.f, r1b = 0.f;
    #pragma unroll
    for (int k = 0; k < 64; k += 2) {
      float2 tk = *(const float2*)&tac_s[wid][k];
      uint2 p = *(const uint2*)&wevp_s[(k >> 1) * 128 + lane * 2];
      res0 = fmaf(tk.x, __uint_as_float(p.x << 16), res0);
      res1 = fmaf(tk.x, __uint_as_float(p.x & 0xFFFF0000u), res1);
      r0b  = fmaf(tk.y, __uint_as_float(p.y << 16), r0b);
      r1b  = fmaf(tk.y, __uint_as_float(p.y & 0xFFFF0000u), r1b);
    }
    out[(size_t)g * DM + lane] = res0 + r0b;
    out[(size_t)g * DM + 64 + lane] = res1 + r1b;
  }
}

extern "C" void kernel_launch(void* const* d_in, const int* in_sizes, int n_in,
                              void* d_out, int out_size, void* d_ws, size_t ws_size,
                              hipStream_t stream) {
  const float* x    = (const float*)d_in[0];
  const int*   ei   = (const int*)d_in[1];
  const float* eemb = (const float*)d_in[2];
  const int*   bidx = (const int*)d_in[3];
  // d_in[4] = n_heads (d_h = 16 -> scale 0.25 hard-coded)
  const float* Wq  = (const float*)d_in[5];
  const float* bq  = (const float*)d_in[6];
  const float* Wk  = (const float*)d_in[7];
  const float* bk  = (const float*)d_in[8];
  const float* Wv  = (const float*)d_in[9];
  const float* bv  = (const float*)d_in[10];
  const float* Wew = (const float*)d_in[11];
  const float* bew = (const float*)d_in[12];
  const float* Wev = (const float*)d_in[13];
  const float* bev = (const float*)d_in[14];
  const float* Wa  = (const float*)d_in[15];
  float* ws  = (float*)d_ws;
  float* out = (float*)d_out;

  // ASUM (float) and CNT (int) are adjacent: one clear for both
  hipMemsetAsync(ws + OFF_ASUM, 0, (size_t)2 * kNodes * sizeof(float), stream);

  k0_combine<<<1, 320, 0, stream>>>(Wq, Wk, Wew, Wa, bq, bk, bew, ws);
  k0b_wsplit<<<64, 256, 0, stream>>>(Wv, Wev, ws);
  k1_node<<<(kNodes + 127) / 128, 512, 0, stream>>>(x, bv, ws);
  k2_edge1<<<(kE + 255) / 256, 256, 0, stream>>>(ei, bidx, eemb, ws);
  k_scan1<<<kScanBlocks, 256, 0, stream>>>(ws);
  k_scan2<<<1, 1024, 0, stream>>>(ws);
  k_fill<<<(kE + 255) / 256, 256, 0, stream>>>(ei, bidx, ws);
  k3_gather<<<4096, 256, 0, stream>>>(eemb, bev, ws, out);
}

// Round 6
// 595.882 us; speedup vs baseline: 1.2305x; 1.1973x over previous
//
#include <hip/hip_runtime.h>

#define DM 128
#define DE 64

static constexpr int kB = 4;
static constexpr int kN = 50000;
static constexpr int kE = 600000;
static constexpr int kNodes = kB * kN;  // 200000

// workspace layout (float units; 4B-aligned ints share the arena)
// ASUM and CNT adjacent -> one memset clears both.
static constexpr size_t OFF_V    = 0;                               // nodes x 128
static constexpr size_t OFF_T    = OFF_V + (size_t)kNodes * DM;     // nodes x 64 (RESERVED, unused)
static constexpr size_t OFF_QA   = OFF_T + (size_t)kNodes * DE;     // nodes
static constexpr size_t OFF_KA   = OFF_QA + kNodes;                 // nodes
static constexpr size_t OFF_ASUM = OFF_KA + kNodes;                 // nodes   (zeroed)
static constexpr size_t OFF_CNT  = OFF_ASUM + kNodes;               // nodes   (int, zeroed)
static constexpr size_t OFF_AEXP = OFF_CNT + kNodes;                // edges
static constexpr size_t OFF_OFFS = OFF_AEXP + kE;                   // nodes (int)
static constexpr size_t OFF_POS  = OFF_OFFS + kNodes;               // edges (int)
static constexpr size_t OFF_BSUM = OFF_POS + kE;                    // 1024 (int)
static constexpr size_t OFF_BPRE = OFF_BSUM + 1024;                 // 1024 (int)
static constexpr size_t OFF_REC  = OFF_BPRE + 1024;                 // edges x float4 (16B aligned)
static constexpr size_t OFF_WQA  = OFF_REC + (size_t)kE * 4;        // 128
static constexpr size_t OFF_WKA  = OFF_WQA + DM;                    // 128
static constexpr size_t OFF_WEWA = OFF_WKA + DM;                    // 64
static constexpr size_t OFF_CB   = OFF_WEWA + DE;                   // 1
// bf16 split of Wv, transposed (j-major) and k-permuted for MFMA frag reads.
static constexpr size_t OFF_WTH  = OFF_CB + 4;
static constexpr size_t OFF_WTL  = OFF_WTH + 8192;
// packed bf16 Wev, pair-interleaved: wevp[(k>>1)*128 + l*2 + (k&1)] =
//   bf16(Wev[k][l]) | bf16(Wev[k][l+64])<<16   (4096 uints)
static constexpr size_t OFF_WEVP = OFF_WTL + 8192;

static constexpr int kScanBlocks = (kNodes + 255) / 256;  // 782

typedef __attribute__((ext_vector_type(8))) short s8;     // 8 bf16 (4 VGPR)
typedef __attribute__((ext_vector_type(4))) float f4;     // MFMA acc

// RNE bf16 of f
__device__ inline unsigned short bf16rne(float f) {
  unsigned u = __float_as_uint(f);
  unsigned r = u + 0x7FFFu + ((u >> 16) & 1u);
  return (unsigned short)(r >> 16);
}

// RNE split: f = bf16(hi) + bf16(lo) + O(2^-17 rel)
__device__ inline void split2(float f, unsigned short& h, unsigned short& lo) {
  h = bf16rne(f);
  float fh = __uint_as_float((unsigned)h << 16);
  lo = bf16rne(f - fh);
}

// K0: fold Wa through the Q/K/Ew projections. wqa = Wq@Wa etc., cb = (bq+bk+bew)·Wa
__global__ void k0_combine(const float* __restrict__ Wq, const float* __restrict__ Wk,
                           const float* __restrict__ Wew, const float* __restrict__ Wa,
                           const float* __restrict__ bq, const float* __restrict__ bk,
                           const float* __restrict__ bew, float* __restrict__ ws) {
  int t = threadIdx.x;
  if (t < DM) {
    float a = 0.f;
    for (int j = 0; j < DM; ++j) a += Wq[t * DM + j] * Wa[j];
    ws[OFF_WQA + t] = a;
  } else if (t < 2 * DM) {
    int i = t - DM;
    float a = 0.f;
    for (int j = 0; j < DM; ++j) a += Wk[i * DM + j] * Wa[j];
    ws[OFF_WKA + i] = a;
  } else if (t < 2 * DM + DE) {
    int i = t - 2 * DM;
    float a = 0.f;
    for (int j = 0; j < DM; ++j) a += Wew[i * DM + j] * Wa[j];
    ws[OFF_WEWA + i] = a;
  }
  if (t == 0) {
    float a = 0.f;
    for (int j = 0; j < DM; ++j) a += (bq[j] + bk[j] + bew[j]) * Wa[j];
    ws[OFF_CB] = a;
  }
}

// K0b: split Wv into bf16 hi/lo (transposed + k-permuted for MFMA frags),
// and pack Wev pair-interleaved for k3's LDS epilogue.
__global__ __launch_bounds__(256) void k0b_wsplit(const float* __restrict__ Wv,
                                                  const float* __restrict__ Wev,
                                                  float* __restrict__ ws) {
  int idx = blockIdx.x * 256 + threadIdx.x;  // 0..16383
  int j = idx & 127, k = idx >> 7;
  float w = Wv[k * DM + j];
  unsigned short hi, lo;
  split2(w, hi, lo);
  int kc = k & 31;
  int kp = (k & ~31) | (((kc >> 2) & 3) << 3) | ((kc >> 4) << 2) | (kc & 3);
  ((short*)(ws + OFF_WTH))[j * 128 + kp] = (short)hi;
  ((short*)(ws + OFF_WTL))[j * 128 + kp] = (short)lo;
  if (idx < 4096) {
    int ke = idx >> 6, l = idx & 63;
    unsigned a = bf16rne(Wev[ke * DM + l]);
    unsigned b = bf16rne(Wev[ke * DM + 64 + l]);
    ((unsigned*)(ws + OFF_WEVP))[(ke >> 1) * 128 + l * 2 + (ke & 1)] = a | (b << 16);
  }
}

// K1: V = x@Wv + bv via split-bf16 MFMA (3 terms: hh + hl + lh, fp32 acc).
__global__ __launch_bounds__(512) void k1_node(const float* __restrict__ x,
                                               const float* __restrict__ bv,
                                               float* __restrict__ ws) {
  __shared__ short xh[128][128];
  __shared__ short xl[128][128];
  __shared__ short wh[128][128];
  __shared__ short wl[128][128];
  const int t = threadIdx.x;
  const int row0 = blockIdx.x * 128;

  // ---- stage W (pre-split, pre-permuted) ----
  const short* wtgh = (const short*)(ws + OFF_WTH);
  const short* wtgl = (const short*)(ws + OFF_WTL);
  #pragma unroll
  for (int i = 0; i < 4; ++i) {
    int idx = t + i * 512;  // 0..2047
    int j = idx >> 4;
    int c8 = (idx & 15) * 8;
    int col = (((c8 >> 3) ^ (j & 7)) << 3);
    *(int4*)&wh[j][col] = *(const int4*)(wtgh + j * 128 + c8);
    *(int4*)&wl[j][col] = *(const int4*)(wtgl + j * 128 + c8);
  }

  // ---- stage x: fp32 -> bf16 hi/lo, k-permuted + swizzled ----
  #pragma unroll
  for (int i = 0; i < 8; ++i) {
    int idx = t + i * 512;  // 0..4095
    int r = idx >> 5;
    int c4 = (idx & 31) * 4;
    int rg = row0 + r; if (rg > kNodes - 1) rg = kNodes - 1;
    float4 v = *(const float4*)(x + (size_t)rg * DM + c4);
    unsigned short h0, h1, h2, h3, l0, l1, l2, l3;
    split2(v.x, h0, l0); split2(v.y, h1, l1);
    split2(v.z, h2, l2); split2(v.w, h3, l3);
    int kc = c4 & 31;
    int cp = (c4 & ~31) | (((kc >> 2) & 3) << 3) | ((kc >> 4) << 2);
    int col = ((((cp >> 3) ^ (r & 7)) << 3)) | (cp & 7);
    *(short4*)&xh[r][col] = make_short4((short)h0, (short)h1, (short)h2, (short)h3);
    *(short4*)&xl[r][col] = make_short4((short)l0, (short)l1, (short)l2, (short)l3);
  }

  // ---- fused qa/ka (exact fp32) ----
  if (t < 256) {
    int r = t & 127;
    int rg = row0 + r;
    if (rg < kNodes) {
      const float* wvec = (t < 128) ? (ws + OFF_WQA) : (ws + OFF_WKA);
      const float* xr = x + (size_t)rg * DM;
      float a = 0.f;
      #pragma unroll
      for (int k = 0; k < DM; k += 4) {
        float4 xv = *(const float4*)(xr + k);
        float4 wv = *(const float4*)(wvec + k);
        a += xv.x * wv.x + xv.y * wv.y + xv.z * wv.z + xv.w * wv.w;
      }
      ((t < 128) ? (ws + OFF_QA) : (ws + OFF_KA))[rg] = a;
    }
  }

  __syncthreads();

  const int l = t & 63;
  const int wid = t >> 6;   // 0..7
  const int wr = wid >> 1;  // 0..3 -> rows wr*32
  const int wc = wid & 1;   // 0..1 -> cols wc*64
  const int lrow = l & 15;
  const int lg = l >> 4;

  f4 acc[2][4];
  #pragma unroll
  for (int i = 0; i < 2; ++i)
    #pragma unroll
    for (int j = 0; j < 4; ++j) acc[i][j] = (f4){0.f, 0.f, 0.f, 0.f};

  #pragma unroll
  for (int ks = 0; ks < 4; ++ks) {
    s8 ah[2], al[2], bh[4], bl[4];
    #pragma unroll
    for (int i = 0; i < 2; ++i) {
      int r = wr * 32 + i * 16 + lrow;
      int col = (((ks * 4 + lg) ^ (r & 7)) << 3);
      ah[i] = *(const s8*)&xh[r][col];
      al[i] = *(const s8*)&xl[r][col];
    }
    #pragma unroll
    for (int j = 0; j < 4; ++j) {
      int r = wc * 64 + j * 16 + lrow;
      int col = (((ks * 4 + lg) ^ (r & 7)) << 3);
      bh[j] = *(const s8*)&wh[r][col];
      bl[j] = *(const s8*)&wl[r][col];
    }
    #pragma unroll
    for (int i = 0; i < 2; ++i)
      #pragma unroll
      for (int j = 0; j < 4; ++j) {
        acc[i][j] = __builtin_amdgcn_mfma_f32_16x16x32_bf16(ah[i], bh[j], acc[i][j], 0, 0, 0);
        acc[i][j] = __builtin_amdgcn_mfma_f32_16x16x32_bf16(ah[i], bl[j], acc[i][j], 0, 0, 0);
        acc[i][j] = __builtin_amdgcn_mfma_f32_16x16x32_bf16(al[i], bh[j], acc[i][j], 0, 0, 0);
      }
  }

  // epilogue: D row = (l>>4)*4 + reg, col = l&15 (m89-verified layout)
  float* V = ws + OFF_V;
  #pragma unroll
  for (int i = 0; i < 2; ++i) {
    int rb = row0 + wr * 32 + i * 16 + lg * 4;
    #pragma unroll
    for (int j = 0; j < 4; ++j) {
      int colj = wc * 64 + j * 16 + lrow;
      float bvv = bv[colj];
      #pragma unroll
      for (int q = 0; q < 4; ++q) {
        int rr = rb + q;
        if (rr < kNodes) V[(size_t)rr * DM + colj] = acc[i][j][q] + bvv;
      }
    }
  }
}

// K2: per-edge logit -> exp -> atomic segment-sum over (b,dst); fused src-degree count
__global__ __launch_bounds__(256) void k2_edge1(const int* __restrict__ ei,
                                                const int* __restrict__ bidx,
                                                const float* __restrict__ eemb,
                                                float* __restrict__ ws) {
  __shared__ float wewa_s[DE];
  __shared__ float cb_s;
  int t = threadIdx.x;
  if (t < DE) wewa_s[t] = ws[OFF_WEWA + t];
  if (t == DE) cb_s = ws[OFF_CB];
  __syncthreads();
  int e = blockIdx.x * 256 + t;
  if (e >= kE) return;
  int s = ei[e];
  int d = ei[kE + e];
  int b = bidx[e];
  const float4* emb = (const float4*)(eemb + (size_t)e * DE);
  float a = 0.f;
  #pragma unroll
  for (int i = 0; i < 16; ++i) {
    float4 v = emb[i];
    a += v.x * wewa_s[i * 4] + v.y * wewa_s[i * 4 + 1] +
         v.z * wewa_s[i * 4 + 2] + v.w * wewa_s[i * 4 + 3];
  }
  float logit = (ws[OFF_QA + b * kN + s] + ws[OFF_KA + b * kN + d] + a + cb_s) * 0.25f;
  float ex = __expf(logit);
  ws[OFF_AEXP + e] = ex;
  unsafeAtomicAdd(&ws[OFF_ASUM + b * kN + d], ex);
  int* wsi = (int*)ws;
  int gs = b * kN + s;
  wsi[OFF_POS + e] = atomicAdd(&wsi[OFF_CNT + gs], 1);
}

// scan step 1: block-local exclusive scan of cnt, block totals to bsum
__global__ __launch_bounds__(256) void k_scan1(float* __restrict__ ws) {
  __shared__ int sh[256];
  int* wsi = (int*)ws;
  const int tid = threadIdx.x;
  const int i = blockIdx.x * 256 + tid;
  int v = (i < kNodes) ? wsi[OFF_CNT + i] : 0;
  int acc = v;
  sh[tid] = acc;
  __syncthreads();
  #pragma unroll
  for (int ofs = 1; ofs < 256; ofs <<= 1) {
    int add = (tid >= ofs) ? sh[tid - ofs] : 0;
    __syncthreads();
    acc += add;
    sh[tid] = acc;
    __syncthreads();
  }
  if (i < kNodes) wsi[OFF_OFFS + i] = acc - v;
  if (tid == 255) wsi[OFF_BSUM + blockIdx.x] = acc;
}

// scan step 2: exclusive scan of block sums (782 <= 1024, single block).
__global__ __launch_bounds__(1024) void k_scan2(float* __restrict__ ws) {
  __shared__ int sh[1024];
  int* wsi = (int*)ws;
  const int tid = threadIdx.x;
  int v = (tid < kScanBlocks) ? wsi[OFF_BSUM + tid] : 0;
  int acc = v;
  sh[tid] = acc;
  __syncthreads();
  for (int ofs = 1; ofs < 1024; ofs <<= 1) {
    int add = (tid >= ofs) ? sh[tid - ofs] : 0;
    __syncthreads();
    acc += add;
    sh[tid] = acc;
    __syncthreads();
  }
  wsi[OFF_BPRE + tid] = acc - v;
}

// fill: resolve each edge into its CSR slot as a 16B record {alpha, gd, e, pad}
__global__ __launch_bounds__(256) void k_fill(const int* __restrict__ ei,
                                              const int* __restrict__ bidx,
                                              float* __restrict__ ws) {
  int e = blockIdx.x * 256 + threadIdx.x;
  if (e >= kE) return;
  int s = ei[e];
  int d = ei[kE + e];
  int b = bidx[e];
  int gs = b * kN + s;
  int gd = b * kN + d;
  const int* wsi = (const int*)ws;
  float alpha = ws[OFF_AEXP + e] / (ws[OFF_ASUM + gd] + 1e-9f);
  int p = wsi[OFF_OFFS + gs] + wsi[OFF_BPRE + (gs >> 8)] + wsi[OFF_POS + e];
  float4 r;
  r.x = alpha;
  r.y = __int_as_float(gd);
  r.z = __int_as_float(e);
  r.w = 0.f;
  ((float4*)(ws + OFF_REC))[p] = r;
}

// gather + fused Wev epilogue (LDS wevp). R4 post-mortem: fully-unrolled
// epilogue ballooned live registers (occupancy stuck at 21% despite LDS move).
// Fixes: __launch_bounds__(256, 8) caps VGPR at 64 (8 waves/EU) and the
// epilogue loop is only 4x-unrolled so the live set stays ~20 VGPR.
__global__ __launch_bounds__(256, 8) void k3_gather(const float* __restrict__ eemb,
                                                    const float* __restrict__ bev,
                                                    float* __restrict__ ws,
                                                    float* __restrict__ out) {
  __shared__ unsigned wevp_s[4096];  // [k>>1][lane][k&1] packed bf16 col-pairs
  __shared__ float tac_s[4][64];     // per-wave T row
  const int t = threadIdx.x;
  const int lane = t & 63;
  const int wid = t >> 6;

  const unsigned* wevpg = (const unsigned*)(ws + OFF_WEVP);
  #pragma unroll 4
  for (int i = 0; i < 16; ++i) wevp_s[t + i * 256] = wevpg[t + i * 256];
  __syncthreads();

  const int gw = (blockIdx.x * 256 + t) >> 6;
  const int nw = (gridDim.x * 256) >> 6;
  const int* wsi = (const int*)ws;
  const float* V = ws + OFF_V;
  const float4* rec = (const float4*)(ws + OFF_REC);
  const float bev0 = bev[lane];
  const float bev1 = bev[64 + lane];

  for (int g = gw; g < kNodes; g += nw) {
    const int start = wsi[OFF_OFFS + g] + wsi[OFF_BPRE + (g >> 8)];
    const int deg = wsi[OFF_CNT + g];
    float o0 = 0.f, o1 = 0.f, tac = 0.f, ss = 0.f;
    for (int base = 0; base < deg; base += 4) {
      const int rem = deg - base;  // >= 1, wave-uniform
      const int c1 = (rem > 1) ? 1 : 0;
      const int c2 = (rem > 2) ? 2 : c1;
      const int c3 = (rem > 3) ? 3 : c2;
      float4 r0 = rec[start + base];
      float4 r1 = rec[start + base + c1];
      float4 r2 = rec[start + base + c2];
      float4 r3 = rec[start + base + c3];
      float a0 = r0.x;
      float a1 = (rem > 1) ? r1.x : 0.f;
      float a2 = (rem > 2) ? r2.x : 0.f;
      float a3 = (rem > 3) ? r3.x : 0.f;
      const size_t gd0 = (size_t)__float_as_int(r0.y) * DM;
      const size_t gd1 = (size_t)__float_as_int(r1.y) * DM;
      const size_t gd2 = (size_t)__float_as_int(r2.y) * DM;
      const size_t gd3 = (size_t)__float_as_int(r3.y) * DM;
      const size_t e0 = (size_t)__float_as_int(r0.z) * DE;
      const size_t e1 = (size_t)__float_as_int(r1.z) * DE;
      const size_t e2 = (size_t)__float_as_int(r2.z) * DE;
      const size_t e3 = (size_t)__float_as_int(r3.z) * DE;
      float v00 = V[gd0 + lane],      v01 = V[gd1 + lane];
      float v02 = V[gd2 + lane],      v03 = V[gd3 + lane];
      float v10 = V[gd0 + 64 + lane], v11 = V[gd1 + 64 + lane];
      float v12 = V[gd2 + 64 + lane], v13 = V[gd3 + 64 + lane];
      float m0 = eemb[e0 + lane],     m1 = eemb[e1 + lane];
      float m2 = eemb[e2 + lane],     m3 = eemb[e3 + lane];
      o0 += a0 * v00 + a1 * v01 + a2 * v02 + a3 * v03;
      o1 += a0 * v10 + a1 * v11 + a2 * v12 + a3 * v13;
      tac += a0 * m0 + a1 * m1 + a2 * m2 + a3 * m3;
      ss += a0 + a1 + a2 + a3;
    }
    // T-row x Wev via LDS broadcast; 4x-unrolled only (register discipline)
    tac_s[wid][lane] = tac;
    float res0 = o0 + ss * bev0;
    float res1 = o1 + ss * bev1;
    float r0b = 0.f, r1b = 0.f;
    #pragma unroll 4
    for (int k = 0; k < 64; k += 2) {
      float2 tk = *(const float2*)&tac_s[wid][k];
      uint2 p = *(const uint2*)&wevp_s[(k >> 1) * 128 + lane * 2];
      res0 = fmaf(tk.x, __uint_as_float(p.x << 16), res0);
      res1 = fmaf(tk.x, __uint_as_float(p.x & 0xFFFF0000u), res1);
      r0b  = fmaf(tk.y, __uint_as_float(p.y << 16), r0b);
      r1b  = fmaf(tk.y, __uint_as_float(p.y & 0xFFFF0000u), r1b);
    }
    out[(size_t)g * DM + lane] = res0 + r0b;
    out[(size_t)g * DM + 64 + lane] = res1 + r1b;
  }
}

extern "C" void kernel_launch(void* const* d_in, const int* in_sizes, int n_in,
                              void* d_out, int out_size, void* d_ws, size_t ws_size,
                              hipStream_t stream) {
  const float* x    = (const float*)d_in[0];
  const int*   ei   = (const int*)d_in[1];
  const float* eemb = (const float*)d_in[2];
  const int*   bidx = (const int*)d_in[3];
  // d_in[4] = n_heads (d_h = 16 -> scale 0.25 hard-coded)
  const float* Wq  = (const float*)d_in[5];
  const float* bq  = (const float*)d_in[6];
  const float* Wk  = (const float*)d_in[7];
  const float* bk  = (const float*)d_in[8];
  const float* Wv  = (const float*)d_in[9];
  const float* bv  = (const float*)d_in[10];
  const float* Wew = (const float*)d_in[11];
  const float* bew = (const float*)d_in[12];
  const float* Wev = (const float*)d_in[13];
  const float* bev = (const float*)d_in[14];
  const float* Wa  = (const float*)d_in[15];
  float* ws  = (float*)d_ws;
  float* out = (float*)d_out;

  // ASUM (float) and CNT (int) are adjacent: one clear for both
  hipMemsetAsync(ws + OFF_ASUM, 0, (size_t)2 * kNodes * sizeof(float), stream);

  k0_combine<<<1, 320, 0, stream>>>(Wq, Wk, Wew, Wa, bq, bk, bew, ws);
  k0b_wsplit<<<64, 256, 0, stream>>>(Wv, Wev, ws);
  k1_node<<<(kNodes + 127) / 128, 512, 0, stream>>>(x, bv, ws);
  k2_edge1<<<(kE + 255) / 256, 256, 0, stream>>>(ei, bidx, eemb, ws);
  k_scan1<<<kScanBlocks, 256, 0, stream>>>(ws);
  k_scan2<<<1, 1024, 0, stream>>>(ws);
  k_fill<<<(kE + 255) / 256, 256, 0, stream>>>(ei, bidx, ws);
  k3_gather<<<4096, 256, 0, stream>>>(eemb, bev, ws, out);
}